// Round 10
// baseline (2704.592 us; speedup 1.0000x reference)
//
#include <hip/hip_runtime.h>
#include <hip/hip_bf16.h>
#include <math.h>

#define N_NODES 100000
#define N_EDGES 1600000
#define NFEAT   128
#define NHID    64
#define NCLASS  16

#define SCAN_NB 391                 // ceil(100000 / 256)
#define NPART   8                   // XCD count; 100000 = 8 * 12500
#define PART_SZ (N_NODES / NPART)   // 12500 (fits 14 bits)
#define BIN_CAP 220000              // E/8 = 200000 expected, +20000 (~47 sigma)

// ---------------------------------------------------------------------------
// Pipeline: zero -> bin (ballot-append, packed (row,col_local)) ->
//           count-from-bins (XCD-local atomics) -> multi-block scan ->
//           fill-from-bins (XCD-local scatter) ->
//           [L1] LDS-tiled gemm1 (bf16*dis epilogue) -> gather1 ->
//           [L2] gemm2 -> gather2 (+log_softmax)
//
// R8 counters: partitioned single-pass fill still had 11x write amplification
// (WRITE 73 MB / 6.4 MB eidx): the 12.8 MB streaming edge reads per partition
// evict dirty eidx lines from the 4 MB XCD L2 before their 16 slots fill.
// Two-phase binning keeps each XCD's phase-2 working set (~2.5 MB: 1.6 MB bin
// stream + 0.8 MB eidx window + cnt/cursor) fully L2-resident -> lines write
// back once. Packing (row<<14)|(col-lo) fits 31 bits (row<2^17, local<12500).
// XCD mapping (blockIdx&7) is a perf heuristic only; correctness holds for
// any dispatch order.
// ---------------------------------------------------------------------------

__global__ void k_zero(int* __restrict__ cnt, int* __restrict__ bcur) {
    int i = blockIdx.x * blockDim.x + threadIdx.x;
    for (int j = i; j < N_NODES; j += gridDim.x * blockDim.x) cnt[j] = 0;
    if (i < NPART) bcur[i] = 0;
}

// Route each edge into its target-partition bin. Wave-aggregated append:
// one atomicAdd per wave per partition present; writes are compacted chunks.
// Note: N_EDGES and the grid stride are both multiples of 64, so the loop
// trip count is wave-uniform (ballot/shfl never see a divergent exit).
__global__ __launch_bounds__(256) void k_bin(const int* __restrict__ rowv,
                                             const int* __restrict__ colv,
                                             int* __restrict__ bcur,
                                             unsigned int* __restrict__ bpk) {
    const int lane = threadIdx.x & 63;
    for (int e = blockIdx.x * blockDim.x + threadIdx.x; e < N_EDGES;
         e += gridDim.x * blockDim.x) {
        int c = colv[e];
        int r = rowv[e];
        int p = c / PART_SZ;                        // 0..7
        unsigned int pk = ((unsigned int)r << 14) | (unsigned int)(c - p * PART_SZ);
        #pragma unroll
        for (int pp = 0; pp < NPART; ++pp) {
            unsigned long long m = __ballot(p == pp);
            if (p == pp) {
                int cs = __popcll(m);
                int leader = __ffsll((unsigned long long)m) - 1;
                int base = 0;
                if (lane == leader) base = atomicAdd(&bcur[pp], cs);
                base = __shfl(base, leader);
                int off = __popcll(m & ((1ull << lane) - 1ull));
                bpk[(size_t)pp * BIN_CAP + base + off] = pk;
            }
        }
    }
}

// Count degrees from bins: partition-local atomics (cnt window ~50 KB, stays
// in the owning XCD's L2 -> no cross-XCD atomic ping-pong).
__global__ __launch_bounds__(256) void k_count_bins(const int* __restrict__ bcur,
                                                    const unsigned int* __restrict__ bpk,
                                                    int* __restrict__ cnt) {
    const int part = blockIdx.x & (NPART - 1);
    const int lo = part * PART_SZ;
    const int nb = gridDim.x >> 3;
    const int bi = blockIdx.x >> 3;
    const int sz = bcur[part];
    const unsigned int* bp = bpk + (size_t)part * BIN_CAP;
    for (int i = bi * blockDim.x + threadIdx.x; i < sz; i += nb * blockDim.x)
        atomicAdd(&cnt[lo + (int)(bp[i] & 16383u)], 1);
}

// --- multi-block exclusive scan of cnt[] -> ptr/cursor, dis = rsqrt(cnt+1) ---
__global__ __launch_bounds__(256) void k_scan_partial(const int* __restrict__ cnt,
                                                      int* __restrict__ bsum) {
    __shared__ int sh[256];
    const int t = threadIdx.x;
    const int i = blockIdx.x * 256 + t;
    int v = (i < N_NODES) ? cnt[i] : 0;
    sh[t] = v;
    __syncthreads();
    for (int off = 128; off > 0; off >>= 1) {
        if (t < off) sh[t] += sh[t + off];
        __syncthreads();
    }
    if (t == 0) bsum[blockIdx.x] = sh[0];
}

__global__ __launch_bounds__(512) void k_scan_bases(const int* __restrict__ bsum,
                                                    int* __restrict__ bbase) {
    __shared__ int sh[512];
    const int t = threadIdx.x;
    int v = (t < SCAN_NB) ? bsum[t] : 0;
    sh[t] = v;
    __syncthreads();
    for (int off = 1; off < 512; off <<= 1) {
        int u = (t >= off) ? sh[t - off] : 0;
        __syncthreads();
        sh[t] += u;
        __syncthreads();
    }
    if (t < SCAN_NB) bbase[t] = sh[t] - v;          // exclusive
}

__global__ __launch_bounds__(256) void k_scan_apply(const int* __restrict__ cnt,
                                                    const int* __restrict__ bbase,
                                                    int* __restrict__ ptr,
                                                    int* __restrict__ cursor,
                                                    float* __restrict__ dis) {
    __shared__ int sh[256];
    const int t = threadIdx.x;
    const int i = blockIdx.x * 256 + t;
    int v = (i < N_NODES) ? cnt[i] : 0;
    sh[t] = v;
    __syncthreads();
    for (int off = 1; off < 256; off <<= 1) {
        int u = (t >= off) ? sh[t - off] : 0;
        __syncthreads();
        sh[t] += u;
        __syncthreads();
    }
    if (i < N_NODES) {
        int base = bbase[blockIdx.x] + sh[t] - v;   // exclusive prefix
        ptr[i] = base;
        cursor[i] = base;
        dis[i] = rsqrtf((float)(v + 1));            // +1 = self-loop
    }
}

// CSR fill from bins: per-XCD working set ~2.5 MB (bin stream + eidx window
// + cursor) -> fully L2-resident, single writeback per eidx line.
__global__ __launch_bounds__(256) void k_fill_bins(const int* __restrict__ bcur,
                                                   const unsigned int* __restrict__ bpk,
                                                   int* __restrict__ cursor,
                                                   int* __restrict__ eidx) {
    const int part = blockIdx.x & (NPART - 1);
    const int lo = part * PART_SZ;
    const int nb = gridDim.x >> 3;
    const int bi = blockIdx.x >> 3;
    const int sz = bcur[part];
    const unsigned int* bp = bpk + (size_t)part * BIN_CAP;
    for (int i = bi * blockDim.x + threadIdx.x; i < sz; i += nb * blockDim.x) {
        unsigned int pk = bp[i];
        int c = lo + (int)(pk & 16383u);
        int pos = atomicAdd(&cursor[c], 1);
        eidx[pos] = (int)(pk >> 14);
    }
}

// xw = x @ W1, LDS-tiled (64x64 tile, K=128). Epilogue scales each output row
// by dis[n] and stores bf16 -> sxw (the gather table).
#define XS_LD 132
#define WS_LD 132
__global__ __launch_bounds__(256) void k_gemm1(const float* __restrict__ x,
                                               const float* __restrict__ W1,
                                               const float* __restrict__ dis,
                                               __hip_bfloat16* __restrict__ sxw) {
    __shared__ float xs[64 * XS_LD];
    __shared__ float ws[64 * WS_LD];
    const int t = threadIdx.x;
    const int bm = blockIdx.x * 64;                // node base (last block ragged)

    #pragma unroll
    for (int it = 0; it < 8; ++it) {
        int f = 4 * (t + 256 * it);                // flat float index in 64x128
        int r = f >> 7, k = f & 127;
        float4 v = make_float4(0.f, 0.f, 0.f, 0.f);
        if (bm + r < N_NODES) v = *(const float4*)&x[(size_t)(bm + r) * NFEAT + k];
        *(float4*)&xs[r * XS_LD + k] = v;
    }
    #pragma unroll
    for (int it = 0; it < 8; ++it) {
        int f = 4 * (t + 256 * it);                // flat float index in 128x64
        int k = f >> 6, c = f & 63;
        float4 v = *(const float4*)&W1[f];
        ws[(c + 0) * WS_LD + k] = v.x;
        ws[(c + 1) * WS_LD + k] = v.y;
        ws[(c + 2) * WS_LD + k] = v.z;
        ws[(c + 3) * WS_LD + k] = v.w;
    }
    __syncthreads();

    const int tx = t & 15, ty = t >> 4;
    float acc[4][4];
    #pragma unroll
    for (int i = 0; i < 4; ++i)
        #pragma unroll
        for (int j = 0; j < 4; ++j) acc[i][j] = 0.f;

    for (int k0 = 0; k0 < NFEAT; k0 += 4) {
        float4 a[4], b[4];
        #pragma unroll
        for (int i = 0; i < 4; ++i)
            a[i] = *(const float4*)&xs[(4 * ty + i) * XS_LD + k0];
        #pragma unroll
        for (int j = 0; j < 4; ++j)
            b[j] = *(const float4*)&ws[(tx + 16 * j) * WS_LD + k0];
        #pragma unroll
        for (int i = 0; i < 4; ++i)
            #pragma unroll
            for (int j = 0; j < 4; ++j)
                acc[i][j] += a[i].x * b[j].x + a[i].y * b[j].y +
                             a[i].z * b[j].z + a[i].w * b[j].w;
    }

    #pragma unroll
    for (int i = 0; i < 4; ++i) {
        int n = bm + 4 * ty + i;
        if (n < N_NODES) {
            float dn = dis[n];
            #pragma unroll
            for (int j = 0; j < 4; ++j)
                sxw[(size_t)n * NHID + tx + 16 * j] =
                    __float2bfloat16(acc[i][j] * dn);
        }
    }
}

// act1[n] = relu( dn * ( sxw[n] + sum_{r in N(n)} sxw[r] ) + b1 )
__global__ __launch_bounds__(256) void k_gather1(const __hip_bfloat16* __restrict__ sxw,
                                                 const int* __restrict__ ptr,
                                                 const int* __restrict__ cnt,
                                                 const int* __restrict__ eidx,
                                                 const float* __restrict__ dis,
                                                 const float* __restrict__ b1,
                                                 float* __restrict__ act1) {
    const int lane = threadIdx.x & 63;
    const int wave = threadIdx.x >> 6;
    const int n = blockIdx.x * 4 + wave;
    if (n >= N_NODES) return;
    const float dn = dis[n];
    const int p0 = ptr[n];
    const int pend = p0 + cnt[n];
    float a0 = __bfloat162float(sxw[(size_t)n * NHID + lane]);   // self term
    float a1 = 0.f, a2 = 0.f, a3 = 0.f;
    int e = p0;
    for (; e + 4 <= pend; e += 4) {
        int r0 = eidx[e + 0], r1 = eidx[e + 1], r2 = eidx[e + 2], r3 = eidx[e + 3];
        a0 += __bfloat162float(sxw[(size_t)r0 * NHID + lane]);
        a1 += __bfloat162float(sxw[(size_t)r1 * NHID + lane]);
        a2 += __bfloat162float(sxw[(size_t)r2 * NHID + lane]);
        a3 += __bfloat162float(sxw[(size_t)r3 * NHID + lane]);
    }
    for (; e < pend; ++e) {
        int r = eidx[e];
        a1 += __bfloat162float(sxw[(size_t)r * NHID + lane]);
    }
    float acc = dn * ((a0 + a1) + (a2 + a3));
    act1[(size_t)n * NHID + lane] = fmaxf(acc + b1[lane], 0.f);
}

// xw2 = act1 @ W2.  One thread per (node, class); W2 (4 KB) L1-resident.
__global__ __launch_bounds__(256) void k_gemm2(const float* __restrict__ act1,
                                               const float* __restrict__ W2,
                                               float* __restrict__ xw2) {
    int tid = blockIdx.x * blockDim.x + threadIdx.x;
    if (tid >= N_NODES * NCLASS) return;
    int n = tid >> 4, cc = tid & 15;
    const float* ar = act1 + (size_t)n * NHID;
    float acc = 0.f;
    #pragma unroll
    for (int k = 0; k < NHID; k += 4) {
        float4 a = *(const float4*)&ar[k];
        acc += a.x * W2[(k + 0) * NCLASS + cc] + a.y * W2[(k + 1) * NCLASS + cc] +
               a.z * W2[(k + 2) * NCLASS + cc] + a.w * W2[(k + 3) * NCLASS + cc];
    }
    xw2[tid] = acc;
}

// Layer-2 aggregate + b2 + log_softmax fused.
__global__ __launch_bounds__(256) void k_gather2(const float* __restrict__ xw2,
                                                 const int* __restrict__ ptr,
                                                 const int* __restrict__ cnt,
                                                 const int* __restrict__ eidx,
                                                 const float* __restrict__ dis,
                                                 const float* __restrict__ b2,
                                                 float* __restrict__ out) {
    const int lane = threadIdx.x & 63;
    const int wave = threadIdx.x >> 6;
    const int n = blockIdx.x * 4 + wave;
    if (n >= N_NODES) return;
    const int f = lane & 15;
    const int g = lane >> 4;
    const float dn = dis[n];
    float acc = (g == 0) ? dn * dn * xw2[(size_t)n * NCLASS + f] : 0.f;
    const int p0 = ptr[n];
    const int c = cnt[n];
    for (int e = p0 + g; e < p0 + c; e += 4) {
        int r = eidx[e];
        acc += dn * dis[r] * xw2[(size_t)r * NCLASS + f];
    }
    acc += __shfl_xor(acc, 16);
    acc += __shfl_xor(acc, 32);
    float v = acc + b2[f];
    float m = v;
    m = fmaxf(m, __shfl_xor(m, 1));
    m = fmaxf(m, __shfl_xor(m, 2));
    m = fmaxf(m, __shfl_xor(m, 4));
    m = fmaxf(m, __shfl_xor(m, 8));
    float ex = expf(v - m);
    float s = ex;
    s += __shfl_xor(s, 1);
    s += __shfl_xor(s, 2);
    s += __shfl_xor(s, 4);
    s += __shfl_xor(s, 8);
    float res = (v - m) - logf(s);
    if (lane < 16) out[(size_t)n * NCLASS + lane] = res;
}

// ---------------------------------------------------------------------------

static inline size_t align256(size_t x) { return (x + 255) & ~(size_t)255; }

extern "C" void kernel_launch(void* const* d_in, const int* in_sizes, int n_in,
                              void* d_out, int out_size, void* d_ws, size_t ws_size,
                              hipStream_t stream) {
    const float* x  = (const float*)d_in[0];
    const int*   ei = (const int*)d_in[1];        // [2, E] flat: row then col
    const float* W1 = (const float*)d_in[2];
    const float* b1 = (const float*)d_in[3];
    const float* W2 = (const float*)d_in[4];
    const float* b2 = (const float*)d_in[5];
    float* out = (float*)d_out;

    const int* rowv = ei;                         // edge_index[0] = sources
    const int* colv = ei + N_EDGES;               // edge_index[1] = targets

    char* ws = (char*)d_ws;
    size_t off = 0;
    int*   cnt    = (int*)(ws + off);  off = align256(off + sizeof(int)   * N_NODES);
    int*   ptr    = (int*)(ws + off);  off = align256(off + sizeof(int)   * N_NODES);
    int*   cursor = (int*)(ws + off);  off = align256(off + sizeof(int)   * N_NODES);
    int*   eidx   = (int*)(ws + off);  off = align256(off + sizeof(int)   * N_EDGES);
    float* dis    = (float*)(ws + off); off = align256(off + sizeof(float) * N_NODES);
    int*   bsum   = (int*)(ws + off);  off = align256(off + sizeof(int)   * 512);
    int*   bbase  = (int*)(ws + off);  off = align256(off + sizeof(int)   * 512);
    int*   bcur   = (int*)(ws + off);  off = align256(off + sizeof(int)   * NPART);
    unsigned int* bpk = (unsigned int*)(ws + off);
    off = align256(off + sizeof(unsigned int) * (size_t)NPART * BIN_CAP);
    __hip_bfloat16* sxw = (__hip_bfloat16*)(ws + off);
    off = align256(off + sizeof(__hip_bfloat16) * N_NODES * NHID);
    float* act1   = (float*)(ws + off); off = align256(off + sizeof(float) * N_NODES * NHID);
    float* xw2    = (float*)(ws + off); off = align256(off + sizeof(float) * N_NODES * NCLASS);
    (void)ws_size; (void)n_in; (void)in_sizes; (void)out_size;

    // 1. zero counters, bin edges by target partition
    k_zero<<<512, 256, 0, stream>>>(cnt, bcur);
    k_bin<<<2048, 256, 0, stream>>>(rowv, colv, bcur, bpk);
    // 2. degree count from bins (XCD-local atomics)
    k_count_bins<<<2048, 256, 0, stream>>>(bcur, bpk, cnt);
    // 3. multi-block prefix scan -> ptr/cursor, dis
    k_scan_partial<<<SCAN_NB, 256, 0, stream>>>(cnt, bsum);
    k_scan_bases<<<1, 512, 0, stream>>>(bsum, bbase);
    k_scan_apply<<<SCAN_NB, 256, 0, stream>>>(cnt, bbase, ptr, cursor, dis);
    // 4. CSR fill from bins (XCD-local scatter, L2-resident windows)
    k_fill_bins<<<2048, 256, 0, stream>>>(bcur, bpk, cursor, eidx);
    // 5. layer-1 transform (LDS-tiled GEMM, bf16 pre-scaled output)
    k_gemm1<<<(N_NODES + 63) / 64, 256, 0, stream>>>(x, W1, dis, sxw);
    // 6. layer-1 aggregate + bias + relu (bf16 gather)
    k_gather1<<<(N_NODES + 3) / 4, 256, 0, stream>>>(sxw, ptr, cnt, eidx, dis, b1, act1);
    // 7. layer-2 transform
    k_gemm2<<<(N_NODES * NCLASS + 255) / 256, 256, 0, stream>>>(act1, W2, xw2);
    // 8. layer-2 aggregate + bias + log_softmax
    k_gather2<<<(N_NODES + 3) / 4, 256, 0, stream>>>(xw2, ptr, cnt, eidx, dis, b2, out);
}

// Round 13
// 449.221 us; speedup vs baseline: 6.0206x; 6.0206x over previous
//
#include <hip/hip_runtime.h>
#include <hip/hip_bf16.h>
#include <math.h>

#define N_NODES 100000
#define N_EDGES 1600000
#define NFEAT   128
#define NHID    64
#define NCLASS  16

#define SCAN_NB 391                 // ceil(100000 / 256)
#define NPART   8                   // XCD count; 100000 = 8 * 12500
#define PART_SZ (N_NODES / NPART)   // 12500 (fits 14 bits)
#define BIN_CAP 220000              // E/8 = 200000 expected, +20000 slack
#define NBLK_BIN 2048
#define CHUNK ((N_EDGES + NBLK_BIN - 1) / NBLK_BIN)   // 782 edges per block

// ---------------------------------------------------------------------------
// Pipeline: bin-count (LDS histogram, no global atomics) -> bin-scan
//           (per-partition block-base prefix) -> bin-write (LDS cursors,
//           compacted bin output) -> count-from-bins (XCD-local atomics) ->
//           node scan -> fill-from-bins (XCD-local scatter) ->
//           [L1] LDS-tiled gemm1 (bf16*dis epilogue) -> gather1 ->
//           [L2] gemm2 -> gather2 (+log_softmax)
//
// R10 lesson: ANY globally-shared running cursor (even wave-aggregated) is a
// serialization disaster: 8 hot counters x ~200K wave-RMWs = 2.27 ms at
// ~100ns cross-XCD ping-pong each. Placement is now fully deterministic:
// per-block histograms + exclusive scan give each block a private window in
// each bin; only LDS atomics order writes within the window.
// R8 lesson (kept): two-phase binning keeps each XCD's fill working set
// (~2.5 MB) L2-resident -> eidx lines write back once (was 11x amplified).
// ---------------------------------------------------------------------------

__global__ void k_zero_cnt(int* __restrict__ cnt) {
    for (int i = blockIdx.x * blockDim.x + threadIdx.x; i < N_NODES;
         i += gridDim.x * blockDim.x)
        cnt[i] = 0;
}

// Pass A: per-block per-partition histogram. Block b owns contiguous chunk
// [b*CHUNK, (b+1)*CHUNK). Output layout bc[p*NBLK_BIN + b] (partition-major
// so the scan reads contiguously).
__global__ __launch_bounds__(256) void k_bin_count(const int* __restrict__ colv,
                                                   int* __restrict__ bc) {
    __shared__ int lc[NPART];
    const int t = threadIdx.x;
    const int b = blockIdx.x;
    if (t < NPART) lc[t] = 0;
    __syncthreads();
    const int start = b * CHUNK;
    const int end = (start + CHUNK < N_EDGES) ? start + CHUNK : N_EDGES;
    for (int e = start + t; e < end; e += 256)
        atomicAdd(&lc[colv[e] / PART_SZ], 1);
    __syncthreads();
    if (t < NPART) bc[t * NBLK_BIN + b] = lc[t];
}

// Pass A.5: for each partition, exclusive-scan the 2048 block counts.
// One 1024-thread block; each thread owns 2 consecutive entries.
__global__ __launch_bounds__(1024) void k_bin_scan(const int* __restrict__ bc,
                                                   int* __restrict__ bbase2,
                                                   int* __restrict__ bcur) {
    __shared__ int sh[1024];
    const int t = threadIdx.x;
    for (int p = 0; p < NPART; ++p) {
        int v0 = bc[p * NBLK_BIN + 2 * t];
        int v1 = bc[p * NBLK_BIN + 2 * t + 1];
        int s = v0 + v1;
        sh[t] = s;
        __syncthreads();
        for (int off = 1; off < 1024; off <<= 1) {
            int u = (t >= off) ? sh[t - off] : 0;
            __syncthreads();
            sh[t] += u;
            __syncthreads();
        }
        int base = sh[t] - s;                       // exclusive over pairs
        bbase2[p * NBLK_BIN + 2 * t] = base;
        bbase2[p * NBLK_BIN + 2 * t + 1] = base + v0;
        if (t == 0) bcur[p] = sh[1023];             // partition total
        __syncthreads();                            // before sh reuse
    }
}

// Pass B: re-read the chunk, claim slots via LDS cursors preloaded with the
// block's global bases, write packed (row<<14)|(col_local) compacted.
__global__ __launch_bounds__(256) void k_bin_write(const int* __restrict__ rowv,
                                                   const int* __restrict__ colv,
                                                   const int* __restrict__ bbase2,
                                                   unsigned int* __restrict__ bpk) {
    __shared__ int lofs[NPART];
    const int t = threadIdx.x;
    const int b = blockIdx.x;
    if (t < NPART) lofs[t] = bbase2[t * NBLK_BIN + b];
    __syncthreads();
    const int start = b * CHUNK;
    const int end = (start + CHUNK < N_EDGES) ? start + CHUNK : N_EDGES;
    for (int e = start + t; e < end; e += 256) {
        int c = colv[e];
        int r = rowv[e];
        int p = c / PART_SZ;
        int pos = atomicAdd(&lofs[p], 1);           // LDS atomic, returns old
        bpk[(size_t)p * BIN_CAP + pos] =
            ((unsigned int)r << 14) | (unsigned int)(c - p * PART_SZ);
    }
}

// Count degrees from bins: partition-local atomics (cnt window ~50 KB stays
// in the owning XCD's L2).
__global__ __launch_bounds__(256) void k_count_bins(const int* __restrict__ bcur,
                                                    const unsigned int* __restrict__ bpk,
                                                    int* __restrict__ cnt) {
    const int part = blockIdx.x & (NPART - 1);
    const int lo = part * PART_SZ;
    const int nb = gridDim.x >> 3;
    const int bi = blockIdx.x >> 3;
    const int sz = bcur[part];
    const unsigned int* bp = bpk + (size_t)part * BIN_CAP;
    for (int i = bi * blockDim.x + threadIdx.x; i < sz; i += nb * blockDim.x)
        atomicAdd(&cnt[lo + (int)(bp[i] & 16383u)], 1);
}

// --- multi-block exclusive scan of cnt[] -> ptr/cursor, dis = rsqrt(cnt+1) ---
__global__ __launch_bounds__(256) void k_scan_partial(const int* __restrict__ cnt,
                                                      int* __restrict__ bsum) {
    __shared__ int sh[256];
    const int t = threadIdx.x;
    const int i = blockIdx.x * 256 + t;
    int v = (i < N_NODES) ? cnt[i] : 0;
    sh[t] = v;
    __syncthreads();
    for (int off = 128; off > 0; off >>= 1) {
        if (t < off) sh[t] += sh[t + off];
        __syncthreads();
    }
    if (t == 0) bsum[blockIdx.x] = sh[0];
}

__global__ __launch_bounds__(512) void k_scan_bases(const int* __restrict__ bsum,
                                                    int* __restrict__ bbase) {
    __shared__ int sh[512];
    const int t = threadIdx.x;
    int v = (t < SCAN_NB) ? bsum[t] : 0;
    sh[t] = v;
    __syncthreads();
    for (int off = 1; off < 512; off <<= 1) {
        int u = (t >= off) ? sh[t - off] : 0;
        __syncthreads();
        sh[t] += u;
        __syncthreads();
    }
    if (t < SCAN_NB) bbase[t] = sh[t] - v;          // exclusive
}

__global__ __launch_bounds__(256) void k_scan_apply(const int* __restrict__ cnt,
                                                    const int* __restrict__ bbase,
                                                    int* __restrict__ ptr,
                                                    int* __restrict__ cursor,
                                                    float* __restrict__ dis) {
    __shared__ int sh[256];
    const int t = threadIdx.x;
    const int i = blockIdx.x * 256 + t;
    int v = (i < N_NODES) ? cnt[i] : 0;
    sh[t] = v;
    __syncthreads();
    for (int off = 1; off < 256; off <<= 1) {
        int u = (t >= off) ? sh[t - off] : 0;
        __syncthreads();
        sh[t] += u;
        __syncthreads();
    }
    if (i < N_NODES) {
        int base = bbase[blockIdx.x] + sh[t] - v;   // exclusive prefix
        ptr[i] = base;
        cursor[i] = base;
        dis[i] = rsqrtf((float)(v + 1));            // +1 = self-loop
    }
}

// CSR fill from bins: per-XCD working set ~2.5 MB -> L2-resident, single
// writeback per eidx line.
__global__ __launch_bounds__(256) void k_fill_bins(const int* __restrict__ bcur,
                                                   const unsigned int* __restrict__ bpk,
                                                   int* __restrict__ cursor,
                                                   int* __restrict__ eidx) {
    const int part = blockIdx.x & (NPART - 1);
    const int lo = part * PART_SZ;
    const int nb = gridDim.x >> 3;
    const int bi = blockIdx.x >> 3;
    const int sz = bcur[part];
    const unsigned int* bp = bpk + (size_t)part * BIN_CAP;
    for (int i = bi * blockDim.x + threadIdx.x; i < sz; i += nb * blockDim.x) {
        unsigned int pk = bp[i];
        int c = lo + (int)(pk & 16383u);
        int pos = atomicAdd(&cursor[c], 1);
        eidx[pos] = (int)(pk >> 14);
    }
}

// xw = x @ W1, LDS-tiled (64x64 tile, K=128). Epilogue scales each output row
// by dis[n] and stores bf16 -> sxw (the gather table).
#define XS_LD 132
#define WS_LD 132
__global__ __launch_bounds__(256) void k_gemm1(const float* __restrict__ x,
                                               const float* __restrict__ W1,
                                               const float* __restrict__ dis,
                                               __hip_bfloat16* __restrict__ sxw) {
    __shared__ float xs[64 * XS_LD];
    __shared__ float ws[64 * WS_LD];
    const int t = threadIdx.x;
    const int bm = blockIdx.x * 64;                // node base (last block ragged)

    #pragma unroll
    for (int it = 0; it < 8; ++it) {
        int f = 4 * (t + 256 * it);                // flat float index in 64x128
        int r = f >> 7, k = f & 127;
        float4 v = make_float4(0.f, 0.f, 0.f, 0.f);
        if (bm + r < N_NODES) v = *(const float4*)&x[(size_t)(bm + r) * NFEAT + k];
        *(float4*)&xs[r * XS_LD + k] = v;
    }
    #pragma unroll
    for (int it = 0; it < 8; ++it) {
        int f = 4 * (t + 256 * it);                // flat float index in 128x64
        int k = f >> 6, c = f & 63;
        float4 v = *(const float4*)&W1[f];
        ws[(c + 0) * WS_LD + k] = v.x;
        ws[(c + 1) * WS_LD + k] = v.y;
        ws[(c + 2) * WS_LD + k] = v.z;
        ws[(c + 3) * WS_LD + k] = v.w;
    }
    __syncthreads();

    const int tx = t & 15, ty = t >> 4;
    float acc[4][4];
    #pragma unroll
    for (int i = 0; i < 4; ++i)
        #pragma unroll
        for (int j = 0; j < 4; ++j) acc[i][j] = 0.f;

    for (int k0 = 0; k0 < NFEAT; k0 += 4) {
        float4 a[4], b[4];
        #pragma unroll
        for (int i = 0; i < 4; ++i)
            a[i] = *(const float4*)&xs[(4 * ty + i) * XS_LD + k0];
        #pragma unroll
        for (int j = 0; j < 4; ++j)
            b[j] = *(const float4*)&ws[(tx + 16 * j) * WS_LD + k0];
        #pragma unroll
        for (int i = 0; i < 4; ++i)
            #pragma unroll
            for (int j = 0; j < 4; ++j)
                acc[i][j] += a[i].x * b[j].x + a[i].y * b[j].y +
                             a[i].z * b[j].z + a[i].w * b[j].w;
    }

    #pragma unroll
    for (int i = 0; i < 4; ++i) {
        int n = bm + 4 * ty + i;
        if (n < N_NODES) {
            float dn = dis[n];
            #pragma unroll
            for (int j = 0; j < 4; ++j)
                sxw[(size_t)n * NHID + tx + 16 * j] =
                    __float2bfloat16(acc[i][j] * dn);
        }
    }
}

// act1[n] = relu( dn * ( sxw[n] + sum_{r in N(n)} sxw[r] ) + b1 )
__global__ __launch_bounds__(256) void k_gather1(const __hip_bfloat16* __restrict__ sxw,
                                                 const int* __restrict__ ptr,
                                                 const int* __restrict__ cnt,
                                                 const int* __restrict__ eidx,
                                                 const float* __restrict__ dis,
                                                 const float* __restrict__ b1,
                                                 float* __restrict__ act1) {
    const int lane = threadIdx.x & 63;
    const int wave = threadIdx.x >> 6;
    const int n = blockIdx.x * 4 + wave;
    if (n >= N_NODES) return;
    const float dn = dis[n];
    const int p0 = ptr[n];
    const int pend = p0 + cnt[n];
    float a0 = __bfloat162float(sxw[(size_t)n * NHID + lane]);   // self term
    float a1 = 0.f, a2 = 0.f, a3 = 0.f;
    int e = p0;
    for (; e + 4 <= pend; e += 4) {
        int r0 = eidx[e + 0], r1 = eidx[e + 1], r2 = eidx[e + 2], r3 = eidx[e + 3];
        a0 += __bfloat162float(sxw[(size_t)r0 * NHID + lane]);
        a1 += __bfloat162float(sxw[(size_t)r1 * NHID + lane]);
        a2 += __bfloat162float(sxw[(size_t)r2 * NHID + lane]);
        a3 += __bfloat162float(sxw[(size_t)r3 * NHID + lane]);
    }
    for (; e < pend; ++e) {
        int r = eidx[e];
        a1 += __bfloat162float(sxw[(size_t)r * NHID + lane]);
    }
    float acc = dn * ((a0 + a1) + (a2 + a3));
    act1[(size_t)n * NHID + lane] = fmaxf(acc + b1[lane], 0.f);
}

// xw2 = act1 @ W2.  One thread per (node, class); W2 (4 KB) L1-resident.
__global__ __launch_bounds__(256) void k_gemm2(const float* __restrict__ act1,
                                               const float* __restrict__ W2,
                                               float* __restrict__ xw2) {
    int tid = blockIdx.x * blockDim.x + threadIdx.x;
    if (tid >= N_NODES * NCLASS) return;
    int n = tid >> 4, cc = tid & 15;
    const float* ar = act1 + (size_t)n * NHID;
    float acc = 0.f;
    #pragma unroll
    for (int k = 0; k < NHID; k += 4) {
        float4 a = *(const float4*)&ar[k];
        acc += a.x * W2[(k + 0) * NCLASS + cc] + a.y * W2[(k + 1) * NCLASS + cc] +
               a.z * W2[(k + 2) * NCLASS + cc] + a.w * W2[(k + 3) * NCLASS + cc];
    }
    xw2[tid] = acc;
}

// Layer-2 aggregate + b2 + log_softmax fused.
__global__ __launch_bounds__(256) void k_gather2(const float* __restrict__ xw2,
                                                 const int* __restrict__ ptr,
                                                 const int* __restrict__ cnt,
                                                 const int* __restrict__ eidx,
                                                 const float* __restrict__ dis,
                                                 const float* __restrict__ b2,
                                                 float* __restrict__ out) {
    const int lane = threadIdx.x & 63;
    const int wave = threadIdx.x >> 6;
    const int n = blockIdx.x * 4 + wave;
    if (n >= N_NODES) return;
    const int f = lane & 15;
    const int g = lane >> 4;
    const float dn = dis[n];
    float acc = (g == 0) ? dn * dn * xw2[(size_t)n * NCLASS + f] : 0.f;
    const int p0 = ptr[n];
    const int c = cnt[n];
    for (int e = p0 + g; e < p0 + c; e += 4) {
        int r = eidx[e];
        acc += dn * dis[r] * xw2[(size_t)r * NCLASS + f];
    }
    acc += __shfl_xor(acc, 16);
    acc += __shfl_xor(acc, 32);
    float v = acc + b2[f];
    float m = v;
    m = fmaxf(m, __shfl_xor(m, 1));
    m = fmaxf(m, __shfl_xor(m, 2));
    m = fmaxf(m, __shfl_xor(m, 4));
    m = fmaxf(m, __shfl_xor(m, 8));
    float ex = expf(v - m);
    float s = ex;
    s += __shfl_xor(s, 1);
    s += __shfl_xor(s, 2);
    s += __shfl_xor(s, 4);
    s += __shfl_xor(s, 8);
    float res = (v - m) - logf(s);
    if (lane < 16) out[(size_t)n * NCLASS + lane] = res;
}

// ---------------------------------------------------------------------------

static inline size_t align256(size_t x) { return (x + 255) & ~(size_t)255; }

extern "C" void kernel_launch(void* const* d_in, const int* in_sizes, int n_in,
                              void* d_out, int out_size, void* d_ws, size_t ws_size,
                              hipStream_t stream) {
    const float* x  = (const float*)d_in[0];
    const int*   ei = (const int*)d_in[1];        // [2, E] flat: row then col
    const float* W1 = (const float*)d_in[2];
    const float* b1 = (const float*)d_in[3];
    const float* W2 = (const float*)d_in[4];
    const float* b2 = (const float*)d_in[5];
    float* out = (float*)d_out;

    const int* rowv = ei;                         // edge_index[0] = sources
    const int* colv = ei + N_EDGES;               // edge_index[1] = targets

    char* ws = (char*)d_ws;
    size_t off = 0;
    int*   cnt    = (int*)(ws + off);  off = align256(off + sizeof(int)   * N_NODES);
    int*   ptr    = (int*)(ws + off);  off = align256(off + sizeof(int)   * N_NODES);
    int*   cursor = (int*)(ws + off);  off = align256(off + sizeof(int)   * N_NODES);
    int*   eidx   = (int*)(ws + off);  off = align256(off + sizeof(int)   * N_EDGES);
    float* dis    = (float*)(ws + off); off = align256(off + sizeof(float) * N_NODES);
    int*   bsum   = (int*)(ws + off);  off = align256(off + sizeof(int)   * 512);
    int*   bbase  = (int*)(ws + off);  off = align256(off + sizeof(int)   * 512);
    int*   bcur   = (int*)(ws + off);  off = align256(off + sizeof(int)   * NPART);
    int*   bc     = (int*)(ws + off);  off = align256(off + sizeof(int)   * NPART * NBLK_BIN);
    int*   bbase2 = (int*)(ws + off);  off = align256(off + sizeof(int)   * NPART * NBLK_BIN);
    unsigned int* bpk = (unsigned int*)(ws + off);
    off = align256(off + sizeof(unsigned int) * (size_t)NPART * BIN_CAP);
    __hip_bfloat16* sxw = (__hip_bfloat16*)(ws + off);
    off = align256(off + sizeof(__hip_bfloat16) * N_NODES * NHID);
    float* act1   = (float*)(ws + off); off = align256(off + sizeof(float) * N_NODES * NHID);
    float* xw2    = (float*)(ws + off); off = align256(off + sizeof(float) * N_NODES * NCLASS);
    (void)ws_size; (void)n_in; (void)in_sizes; (void)out_size;

    // 1. deterministic two-pass binning (no global atomics)
    k_zero_cnt<<<512, 256, 0, stream>>>(cnt);
    k_bin_count<<<NBLK_BIN, 256, 0, stream>>>(colv, bc);
    k_bin_scan<<<1, 1024, 0, stream>>>(bc, bbase2, bcur);
    k_bin_write<<<NBLK_BIN, 256, 0, stream>>>(rowv, colv, bbase2, bpk);
    // 2. degree count from bins (XCD-local atomics)
    k_count_bins<<<2048, 256, 0, stream>>>(bcur, bpk, cnt);
    // 3. multi-block prefix scan -> ptr/cursor, dis
    k_scan_partial<<<SCAN_NB, 256, 0, stream>>>(cnt, bsum);
    k_scan_bases<<<1, 512, 0, stream>>>(bsum, bbase);
    k_scan_apply<<<SCAN_NB, 256, 0, stream>>>(cnt, bbase, ptr, cursor, dis);
    // 4. CSR fill from bins (XCD-local scatter, L2-resident windows)
    k_fill_bins<<<2048, 256, 0, stream>>>(bcur, bpk, cursor, eidx);
    // 5. layer-1 transform (LDS-tiled GEMM, bf16 pre-scaled output)
    k_gemm1<<<(N_NODES + 63) / 64, 256, 0, stream>>>(x, W1, dis, sxw);
    // 6. layer-1 aggregate + bias + relu (bf16 gather)
    k_gather1<<<(N_NODES + 3) / 4, 256, 0, stream>>>(sxw, ptr, cnt, eidx, dis, b1, act1);
    // 7. layer-2 transform
    k_gemm2<<<(N_NODES * NCLASS + 255) / 256, 256, 0, stream>>>(act1, W2, xw2);
    // 8. layer-2 aggregate + bias + log_softmax
    k_gather2<<<(N_NODES + 3) / 4, 256, 0, stream>>>(xw2, ptr, cnt, eidx, dis, b2, out);
}